// Round 10
// baseline (491.331 us; speedup 1.0000x reference)
//
#include <hip/hip_runtime.h>
#include <hip/hip_bf16.h>
#include <math.h>

constexpr int BB = 2;
constexpr int LL = 1024;
constexpr int DD = 768;
constexpr int HH = 12;
constexpr int NEz = 42;
constexpr int MM = 8;
constexpr int NPp = 1722;
constexpr int CC = 97;
constexpr int FF = 256;
constexpr int PAIRS = NEz * NEz;         // 1764
constexpr int TOTAL = BB * NPp;          // 3444
constexpr int MTv = 256;                 // rows per k_bil tile
constexpr int NTt = 14;                  // tiles (padded 3584)
constexpr int PADR = 3584;
constexpr int NOGv = 36;                 // o-groups
constexpr int NWGv = 1008;               // 8 XCD-slots * 126
constexpr int EWSZ = BB * NEz * FF;      // 21504

typedef float f32x4 __attribute__((ext_vector_type(4)));
typedef short bf16x8 __attribute__((ext_vector_type(8)));
typedef unsigned int u32x2 __attribute__((ext_vector_type(2)));

__device__ inline short f2bs(float x) {
    __hip_bfloat16 b = __float2bfloat16(x);
    return *(short*)&b;
}
__device__ inline void gload16(const void* g, void* l) {
    __builtin_amdgcn_global_load_lds((const __attribute__((address_space(1))) unsigned int*)g,
                                     (__attribute__((address_space(3))) unsigned int*)l, 16, 0, 0);
}

// ---------------- K2: ent_emb = masked logsumexp over M mentions ----------------
__global__ void k_ent_emb(const float* __restrict__ seq, const int* __restrict__ midx,
                          const int* __restrict__ mmask, float* __restrict__ ent_emb) {
    int be = blockIdx.x;
    int b = be / NEz;
    int tid = threadIdx.x;
    int idx[MM], msk[MM];
#pragma unroll
    for (int m = 0; m < MM; ++m) {
        idx[m] = midx[be * MM + m];
        msk[m] = mmask[be * MM + m];
    }
    const float* sb = seq + (size_t)b * LL * DD;
    for (int d = tid; d < DD; d += 256) {
        float v[MM];
        float mx = -1e30f;
#pragma unroll
        for (int m = 0; m < MM; ++m) {
            v[m] = msk[m] ? sb[(size_t)idx[m] * DD + d] : -1e30f;
            mx = fmaxf(mx, v[m]);
        }
        float s = 0.f;
#pragma unroll
        for (int m = 0; m < MM; ++m) s += expf(v[m] - mx);
        ent_emb[(size_t)be * DD + d] = mx + logf(s);
    }
}

// ---------------- K3: ent_att ----------------
__global__ void k_ent_att(const float* __restrict__ att, const int* __restrict__ midx,
                          const int* __restrict__ mmask, float* __restrict__ ea) {
    int beh = blockIdx.x;
    int h = beh % HH;
    int be = beh / HH;
    int b = be / NEz;
    int tid = threadIdx.x;
    int idx[MM], msk[MM];
    float msum = 0.f;
#pragma unroll
    for (int m = 0; m < MM; ++m) {
        idx[m] = midx[be * MM + m];
        msk[m] = mmask[be * MM + m];
        msum += (float)msk[m];
    }
    float inv = 1.f / msum;
    const float* ab = att + ((size_t)b * HH + h) * LL * LL;
#pragma unroll
    for (int li = 0; li < 4; ++li) {
        int l = tid + li * 256;
        float acc = 0.f;
#pragma unroll
        for (int m = 0; m < MM; ++m)
            if (msk[m]) acc += ab[(size_t)idx[m] * LL + l];
        ea[(size_t)beh * LL + l] = acc * inv;
    }
}

// ---------------- K4a: per (b, l-chunk of 8): ht partial sums + projections ------
__global__ void k_pairAB(const float* __restrict__ ea, const float* __restrict__ seq,
                         const float* __restrict__ Wl, float* __restrict__ szp) {
    int lcb = blockIdx.x;   // 0..127
    int b = blockIdx.y;
    int l0 = lcb * 8;
    int tid = threadIdx.x;  // 384 = 6 waves
    int lane = tid & 63;
    int e1 = (tid >> 6) * 8 + (lane >> 3);
    int l = lane & 7;

    __shared__ float S[NEz][HH][9];
    __shared__ float sw[8][3];
    __shared__ float swp[24][17];

    for (int idx = tid; idx < NEz * HH * 8; idx += 384) {
        int e = idx / 96, rem = idx % 96;
        int h = rem / 8, ll = rem % 8;
        S[e][h][ll] = ea[((size_t)(b * NEz + e) * HH + h) * LL + l0 + ll];
    }
    {
        int cpair = tid % 24, s = tid / 24;
        if (s < 16) {
            int ll = cpair / 3, kk = cpair % 3;
            const float* sr = seq + ((size_t)b * LL + l0 + ll) * DD;
            float p = 0.f;
            for (int d = s * 48; d < s * 48 + 48; ++d) p += sr[d] * Wl[d * 3 + kk];
            swp[cpair][s] = p;
        }
    }
    __syncthreads();
    if (tid < 24) {
        float s = 0.f;
#pragma unroll
        for (int i = 0; i < 16; ++i) s += swp[tid][i];
        sw[tid / 3][tid % 3] = s;
    }
    __syncthreads();

    bool act = e1 < NEz;
    float e1r[HH];
#pragma unroll
    for (int h = 0; h < HH; ++h) e1r[h] = act ? S[e1][h][l] : 0.f;
    float sw0 = sw[l][0], sw1 = sw[l][1], sw2 = sw[l][2];

    for (int e2 = 0; e2 < NEz; ++e2) {
        float ht = 0.f;
#pragma unroll
        for (int h = 0; h < HH; ++h) ht += e1r[h] * S[e2][h][l];
        ht *= (1.0f / HH);
        float v0 = ht, v1 = ht * sw0, v2 = ht * sw1, v3 = ht * sw2;
#pragma unroll
        for (int off = 1; off < 8; off <<= 1) {
            v0 += __shfl_xor(v0, off);
            v1 += __shfl_xor(v1, off);
            v2 += __shfl_xor(v2, off);
            v3 += __shfl_xor(v3, off);
        }
        if (act && l == 0) {
            float4 o4 = make_float4(v0, v1, v2, v3);
            *(float4*)&szp[(((size_t)(b * PAIRS + e1 * NEz + e2)) * 128 + lcb) * 4] = o4;
        }
    }
}

// ---------------- K4b: reduce partials -> zz (8 threads per pair) ----------------
__global__ void k_zz(const float* __restrict__ szp, const float* __restrict__ blin,
                     float* __restrict__ zz) {
    int idx = blockIdx.x * 256 + threadIdx.x;
    int bp = idx >> 3, s8 = idx & 7;
    if (bp >= BB * PAIRS) return;
    const float4* s = (const float4*)(szp + (size_t)bp * 512) + s8 * 16;
    float v0 = 0.f, v1 = 0.f, v2 = 0.f, v3 = 0.f;
#pragma unroll
    for (int i = 0; i < 16; ++i) {
        float4 a = s[i];
        v0 += a.x; v1 += a.y; v2 += a.z; v3 += a.w;
    }
#pragma unroll
    for (int off = 1; off < 8; off <<= 1) {
        v0 += __shfl_xor(v0, off);
        v1 += __shfl_xor(v1, off);
        v2 += __shfl_xor(v2, off);
        v3 += __shfl_xor(v3, off);
    }
    if (s8 == 0) {
        float inv = 1.f / (v0 + 1e-5f);
        float4 o4 = make_float4(v1 * inv + blin[0], v2 * inv + blin[1], v3 * inv + blin[2], 0.f);
        *(float4*)&zz[(size_t)bp * 4] = o4;
    }
}

// ---------------- K5: EW partials, d-split 4x (summed in k_prep) -----------------
__global__ void k_ew(const float* __restrict__ ent_emb, const float* __restrict__ Wh,
                     const float* __restrict__ bh, const float* __restrict__ Wt,
                     const float* __restrict__ bt, float* __restrict__ EWph,
                     float* __restrict__ EWpt) {
    int be = blockIdx.x;            // 84
    int dc = blockIdx.y;            // 4 chunks of 192
    int tid = threadIdx.x;          // 256
    __shared__ float e[192];
    if (tid < 192) e[tid] = ent_emb[(size_t)be * DD + dc * 192 + tid];
    __syncthreads();
    float ah = (dc == 0) ? bh[tid] : 0.f;
    float at = (dc == 0) ? bt[tid] : 0.f;
    const float* Whb = Wh + (size_t)dc * 192 * FF;
    const float* Wtb = Wt + (size_t)dc * 192 * FF;
    for (int d = 0; d < 192; ++d) {
        float ev = e[d];
        ah += ev * Whb[(size_t)d * FF + tid];
        at += ev * Wtb[(size_t)d * FF + tid];
    }
    EWph[(size_t)dc * EWSZ + be * FF + tid] = ah;
    EWpt[(size_t)dc * EWSZ + be * FF + tid] = at;
}

// ---------------- K6a: Wf = pre-swizzled 32KB LDS images of W_bil ----------------
// image (o, kc): byte (c*128 + k16*16) ^ ((c&7)<<4) = bf16x8 of W[o][kc*64+k16*8..+8][c]
__global__ void k_wt(const float* __restrict__ Wb, char* __restrict__ Wf) {
    int o = blockIdx.x >> 2, kc = blockIdx.x & 3;
    int tid = threadIdx.x;          // 256
    __shared__ float t64[64][257];
    const float* src = Wb + (size_t)o * FF * FF + (size_t)(kc * 64) * FF;
#pragma unroll
    for (int i = 0; i < 64; ++i) {
        int flat = i * 256 + tid;
        t64[flat >> 8][flat & 255] = src[flat];
    }
    __syncthreads();
    char* dst = Wf + ((size_t)o * 4 + kc) * 32768;
#pragma unroll
    for (int i = 0; i < 8; ++i) {
        int u = i * 256 + tid;
        int c = u >> 3, k16 = u & 7;
        bf16x8 v;
#pragma unroll
        for (int j = 0; j < 8; ++j) v[j] = f2bs(t64[k16 * 8 + j][c]);
        *(bf16x8*)(dst + ((c * 128 + k16 * 16) ^ ((c & 7) << 4))) = v;
    }
}

// ---------------- K6b: HSf (pre-swizzled 32KB A images, 256 rows) + TSt ----------
// grid = 14 mt x 4 kc; image idx = mt*4 + kc covers rows 256, k = kc*64..+64
__global__ void k_prep(const float* __restrict__ EWph, const float* __restrict__ EWpt,
                       const float* __restrict__ zz, const float* __restrict__ Wseg,
                       const float* __restrict__ bseg, const int* __restrict__ hts,
                       char* __restrict__ HSf, unsigned short* __restrict__ TSt) {
    int mt = blockIdx.x >> 2, kc = blockIdx.x & 3;
    int tid = threadIdx.x;          // 256
    int p0 = mt * MTv;

    __shared__ int offh[256], offt[256];
    __shared__ float zr[256][3];
    __shared__ float wsg[4][64];

    {
        int p = p0 + tid;
        if (p < TOTAL) {
            int b = p / NPp;
            int e1 = hts[p * 2], e2 = hts[p * 2 + 1];
            offh[tid] = (b * NEz + e1) * FF;
            offt[tid] = (b * NEz + e2) * FF;
            float4 z4 = *(const float4*)(zz + (size_t)(b * PAIRS + e1 * NEz + e2) * 4);
            zr[tid][0] = z4.x; zr[tid][1] = z4.y; zr[tid][2] = z4.z;
        } else {
            offh[tid] = -1; offt[tid] = -1;
            zr[tid][0] = zr[tid][1] = zr[tid][2] = 0.f;
        }
        if (tid < 64) {
            int c = kc * 64 + tid;
            wsg[0][tid] = Wseg[c];
            wsg[1][tid] = Wseg[FF + c];
            wsg[2][tid] = Wseg[2 * FF + c];
            wsg[3][tid] = bseg[c];
        }
    }
    __syncthreads();

    // A image: 2048 slots of 16B, coalesced writes
    char* dst = HSf + (size_t)(mt * 4 + kc) * 32768;
#pragma unroll
    for (int it = 0; it < 8; ++it) {
        int slot = it * 256 + tid;
        int r = slot >> 3;
        int kin = (slot & 7) * 16;               // swizzled byte-in-row
        int kb = kin ^ ((r & 7) << 4);           // unswizzled k-byte
        int cl0 = kb >> 1;                       // col within chunk (0..63)
        int oh = offh[r];
        bf16x8 v = {0, 0, 0, 0, 0, 0, 0, 0};
        if (oh >= 0) {
            float z0 = zr[r][0], z1 = zr[r][1], z2 = zr[r][2];
            int gc = oh + kc * 64 + cl0;
#pragma unroll
            for (int j = 0; j < 8; ++j) {
                int cl = cl0 + j;
                float ew = EWph[gc + j] + EWph[EWSZ + gc + j] +
                           EWph[2 * EWSZ + gc + j] + EWph[3 * EWSZ + gc + j];
                float ht = fmaxf(z0 * wsg[0][cl] + z1 * wsg[1][cl] +
                                 z2 * wsg[2][cl] + wsg[3][cl], 0.f);
                v[j] = f2bs(tanhf(ew + ht));
            }
        }
        *(bf16x8*)(dst + r * 128 + kin) = v;
    }
    // TSt[c][p0..p0+256): thread = (c 64) x (rg 4); vector stores of 8 rows
    {
        int cl = tid >> 2, rgg = tid & 3;
        int c = kc * 64 + cl;
        float w0 = wsg[0][cl], w1 = wsg[1][cl], w2 = wsg[2][cl], w3 = wsg[3][cl];
#pragma unroll
        for (int v8 = 0; v8 < 8; ++v8) {
            int rbase = rgg * 64 + v8 * 8;
            bf16x8 w;
#pragma unroll
            for (int j = 0; j < 8; ++j) {
                int r = rbase + j;
                int ot = offt[r];
                short vv = 0;
                if (ot >= 0) {
                    float ew = EWpt[ot + c] + EWpt[EWSZ + ot + c] +
                               EWpt[2 * EWSZ + ot + c] + EWpt[3 * EWSZ + ot + c];
                    float ht = fmaxf(zr[r][0] * w0 + zr[r][1] * w1 + zr[r][2] * w2 + w3, 0.f);
                    vv = f2bs(tanhf(ew + ht));
                }
                w[j] = vv;
            }
            *(bf16x8*)(TSt + (size_t)c * PADR + p0 + rbase) = w;
        }
    }
}

// ---------------- K6c: bilinear, M=256 kr-split, wave-tile 128x64 ---------------
// 512 thr = 8 waves (wr2 x wc4).  A (256x128 k-half) resident in LDS (64KB);
// B double-buffered 2x32KB, counted vmcnt(4); TS in 64 VGPR; atomicAdd combine.
#define STAGE(C, BUF) do { \
    int c_ = (C); \
    int o_ = og + NOGv * (c_ >> 1); \
    int kc_ = kr2 + (c_ & 1); \
    const char* Bs_ = Wf + ((size_t)(o_ * 4 + kc_)) * 32768; \
    _Pragma("unroll") \
    for (int i_ = 0; i_ < 4; ++i_) \
        gload16(Bs_ + (i_ * 512 + tid) * 16, Bb[BUF] + (i_ * 512 + tid) * 16); \
} while (0)

__launch_bounds__(512, 2)
__global__ void k_bil(const char* __restrict__ HSf, const unsigned short* __restrict__ TSt,
                      const char* __restrict__ Wf, const float* __restrict__ bbil,
                      float* __restrict__ out) {
    int f = blockIdx.x;
    int xcd = f & 7, sub = f >> 3;            // sub 0..125
    int q = xcd >> 1, kr = xcd & 1;
    int og = q + 4 * (sub / 14);              // balanced: q + 4j, j 0..8
    int mt = sub % 14;
    int kr2 = kr * 2;
    int p0 = mt * MTv;
    int nO = (og < 25) ? 3 : 2;

    int tid = threadIdx.x;
    int lane = tid & 63, w = tid >> 6;
    int wr = w >> 2, wc = w & 3;
    int lr = lane & 15, lg = lane >> 4;

    __shared__ char A_l[65536];
    __shared__ char Bb[2][32768];
    __shared__ float red[MTv][4];

    // TS fragments in registers: o-independent, loaded once (64 VGPR)
    u32x2 tsv[8][4];
#pragma unroll
    for (int mi = 0; mi < 8; ++mi)
#pragma unroll
        for (int ni = 0; ni < 4; ++ni)
            tsv[mi][ni] = *(const u32x2*)(TSt + (size_t)(wc * 64 + ni * 16 + lr) * PADR +
                                          p0 + wr * 128 + mi * 16 + lg * 4);
    __builtin_amdgcn_sched_barrier(0);

    // prologue: A k-half (2 images, 64KB), then B chunks 0,1
    {
        const char* As = HSf + (size_t)(mt * 4 + kr2) * 32768;
#pragma unroll
        for (int i = 0; i < 8; ++i)
            gload16(As + (i * 512 + tid) * 16, A_l + (i * 512 + tid) * 16);
    }
    __builtin_amdgcn_sched_barrier(0);
    STAGE(0, 0);
    __builtin_amdgcn_sched_barrier(0);
    STAGE(1, 1);

    f32x4 acc[8][4];
#pragma unroll
    for (int mi = 0; mi < 8; ++mi)
#pragma unroll
        for (int ni = 0; ni < 4; ++ni) acc[mi][ni] = (f32x4){0.f, 0.f, 0.f, 0.f};

    int T = 2 * nO;
    for (int t = 0; t < T; ++t) {
        int cur = t & 1;
        __builtin_amdgcn_sched_barrier(0);
        asm volatile("s_waitcnt vmcnt(4)" ::: "memory");   // TS+A+B_t landed; B_{t+1} in flight
        __builtin_amdgcn_sched_barrier(0);
        __builtin_amdgcn_s_barrier();
        __builtin_amdgcn_sched_barrier(0);

        const char* Ac = A_l + cur * 32768;                // kc2 = t&1
        const char* Bc = Bb[cur];

        bf16x8 a0[8], b0[4];
#pragma unroll
        for (int mi = 0; mi < 8; ++mi) {
            int r = wr * 128 + mi * 16 + lr;
            a0[mi] = *(const bf16x8*)(Ac + ((r * 128 + lg * 16) ^ ((r & 7) << 4)));
        }
#pragma unroll
        for (int ni = 0; ni < 4; ++ni) {
            int c = wc * 64 + ni * 16 + lr;
            b0[ni] = *(const bf16x8*)(Bc + ((c * 128 + lg * 16) ^ ((c & 7) << 4)));
        }
        __builtin_amdgcn_sched_barrier(0);
        asm volatile("s_waitcnt lgkmcnt(0)" ::: "memory");
        __builtin_amdgcn_sched_barrier(0);
        __builtin_amdgcn_s_setprio(1);
#pragma unroll
        for (int mi = 0; mi < 8; ++mi)
#pragma unroll
            for (int ni = 0; ni < 4; ++ni)
                acc[mi][ni] = __builtin_amdgcn_mfma_f32_16x16x32_bf16(a0[mi], b0[ni], acc[mi][ni], 0, 0, 0);
        __builtin_amdgcn_s_setprio(0);

        bf16x8 a1[8], b1[4];
#pragma unroll
        for (int mi = 0; mi < 8; ++mi) {
            int r = wr * 128 + mi * 16 + lr;
            a1[mi] = *(const bf16x8*)(Ac + ((r * 128 + 64 + lg * 16) ^ ((r & 7) << 4)));
        }
#pragma unroll
        for (int ni = 0; ni < 4; ++ni) {
            int c = wc * 64 + ni * 16 + lr;
            b1[ni] = *(const bf16x8*)(Bc + ((c * 128 + 64 + lg * 16) ^ ((c & 7) << 4)));
        }
        __builtin_amdgcn_sched_barrier(0);
        asm volatile("s_waitcnt lgkmcnt(0)" ::: "memory");  // our reads of Bb[cur] retired
        __builtin_amdgcn_sched_barrier(0);
        __builtin_amdgcn_s_barrier();                       // all waves done reading Bb[cur]
        __builtin_amdgcn_sched_barrier(0);

        int tt = (t + 2 < T) ? t + 2 : T - 1;               // clamp keeps vmcnt uniform
        STAGE(tt, cur);
        __builtin_amdgcn_sched_barrier(0);
        __builtin_amdgcn_s_setprio(1);
#pragma unroll
        for (int mi = 0; mi < 8; ++mi)
#pragma unroll
            for (int ni = 0; ni < 4; ++ni)
                acc[mi][ni] = __builtin_amdgcn_mfma_f32_16x16x32_bf16(a1[mi], b1[ni], acc[mi][ni], 0, 0, 0);
        __builtin_amdgcn_s_setprio(0);

        if (t & 1) {
            int o = og + NOGv * (t >> 1);
#pragma unroll
            for (int mi = 0; mi < 8; ++mi) {
                float s0 = 0.f, s1 = 0.f, s2 = 0.f, s3 = 0.f;
#pragma unroll
                for (int ni = 0; ni < 4; ++ni) {
                    unsigned lo = tsv[mi][ni][0], hi = tsv[mi][ni][1];
                    s0 += acc[mi][ni][0] * __uint_as_float(lo << 16);
                    s1 += acc[mi][ni][1] * __uint_as_float(lo & 0xFFFF0000u);
                    s2 += acc[mi][ni][2] * __uint_as_float(hi << 16);
                    s3 += acc[mi][ni][3] * __uint_as_float(hi & 0xFFFF0000u);
                    acc[mi][ni] = (f32x4){0.f, 0.f, 0.f, 0.f};
                }
#pragma unroll
                for (int off = 1; off < 16; off <<= 1) {
                    s0 += __shfl_xor(s0, off);
                    s1 += __shfl_xor(s1, off);
                    s2 += __shfl_xor(s2, off);
                    s3 += __shfl_xor(s3, off);
                }
                if (lr == 0) {
                    int rb = wr * 128 + mi * 16 + lg * 4;
                    red[rb + 0][wc] = s0;
                    red[rb + 1][wc] = s1;
                    red[rb + 2][wc] = s2;
                    red[rb + 3][wc] = s3;
                }
            }
            __builtin_amdgcn_sched_barrier(0);
            asm volatile("s_waitcnt lgkmcnt(0)" ::: "memory");
            __builtin_amdgcn_sched_barrier(0);
            __builtin_amdgcn_s_barrier();
            __builtin_amdgcn_sched_barrier(0);
            if (tid < MTv) {
                int p = p0 + tid;
                if (p < TOTAL) {
                    float v = red[tid][0] + red[tid][1] + red[tid][2] + red[tid][3] +
                              (kr == 0 ? bbil[o] : 0.f);
                    atomicAdd(out + (size_t)p * CC + o, v);
                }
            }
        }
    }
}
#undef STAGE

extern "C" void kernel_launch(void* const* d_in, const int* in_sizes, int n_in,
                              void* d_out, int out_size, void* d_ws, size_t ws_size,
                              hipStream_t stream) {
    const float* seq   = (const float*)d_in[0];
    const float* att   = (const float*)d_in[1];
    const int*   midx  = (const int*)d_in[2];
    const int*   mmask = (const int*)d_in[3];
    const int*   hts   = (const int*)d_in[4];
    const float* Wlin  = (const float*)d_in[5];
    const float* blin  = (const float*)d_in[6];
    const float* Wseg  = (const float*)d_in[7];
    const float* bseg  = (const float*)d_in[8];
    const float* Whead = (const float*)d_in[9];
    const float* bhead = (const float*)d_in[10];
    const float* Wtail = (const float*)d_in[11];
    const float* btail = (const float*)d_in[12];
    const float* Wbil  = (const float*)d_in[13];
    const float* bbil  = (const float*)d_in[14];
    float* out = (float*)d_out;

    float* ws = (float*)d_ws;
    float* ent_emb = ws;                                     // 64512 f
    float* ea      = ent_emb + BB * NEz * DD;                // 1032192 f
    float* szp     = ea + (size_t)BB * NEz * HH * LL;        // 1806336 f
    float* zz      = szp + (size_t)BB * PAIRS * 128 * 4;     // 14112 f
    float* EWph    = zz + (size_t)BB * PAIRS * 4;            // 4*21504 f
    float* EWpt    = EWph + 4 * EWSZ;                        // 4*21504 f
    char* Wf       = (char*)(EWpt + 4 * EWSZ);               // 97*4*32768 B
    char* HSf      = Wf + (size_t)CC * 4 * 32768;            // 14*4*32768 B
    unsigned short* TSt = (unsigned short*)(HSf + (size_t)NTt * 4 * 32768);  // 256*3584

    hipMemsetAsync(out, 0, (size_t)out_size * sizeof(float), stream);
    k_ent_emb<<<BB * NEz, 256, 0, stream>>>(seq, midx, mmask, ent_emb);
    k_ent_att<<<BB * NEz * HH, 256, 0, stream>>>(att, midx, mmask, ea);
    k_pairAB<<<dim3(128, BB), 384, 0, stream>>>(ea, seq, Wlin, szp);
    k_zz<<<(BB * PAIRS * 8 + 255) / 256, 256, 0, stream>>>(szp, blin, zz);
    k_ew<<<dim3(BB * NEz, 4), 256, 0, stream>>>(ent_emb, Whead, bhead, Wtail, btail, EWph, EWpt);
    k_wt<<<CC * 4, 256, 0, stream>>>(Wbil, Wf);
    k_prep<<<NTt * 4, 256, 0, stream>>>(EWph, EWpt, zz, Wseg, bseg, hts, HSf, TSt);
    k_bil<<<NWGv, 512, 0, stream>>>(HSf, TSt, Wf, bbil, out);
}